// Round 11
// baseline (5497.691 us; speedup 1.0000x reference)
//
#include <hip/hip_runtime.h>
#include <hip/hip_bf16.h>
#include <hip/hip_fp16.h>

// LiquidLinear: xin = x@Wi^T + bi ; scan: h' = (1-sig(tau))h + sig(tau)tanh(xin_t + h@Wr^T + br)
// outs = hs@Wo^T + bo ; outputs = [outs (B,S,DOUT) fp32][h_final (B,H) fp32]
// B=64 S=1024 DIN=H=DOUT=512
//
// R11: R9/R10 exchange-free scan, with the register-budget fix done RIGHT:
// __attribute__((amdgpu_flat_work_group_size(512,512), amdgpu_waves_per_eu(2,2))).
// R9 (512,2) and R10 (512,1) produced IDENTICAL code at exactly 128 VGPRs =
// the 4-waves/EU budget: launch_bounds' 2nd arg is only a MINIMUM; the GCN
// scheduler still TARGETS 4 waves/EU and spills the 184 weight VGPRs to
// scratch (LDS already caps the CU at 2 waves/EU, so that occupancy is
// unreachable -- pure loss). Pinning min=max=2 waves/EU sets the budget to
// 256 and removes the incentive to shrink: weights stay in registers.

typedef _Float16 f16x8 __attribute__((ext_vector_type(8)));
typedef float f32x4 __attribute__((ext_vector_type(4)));
typedef float floatv4 __attribute__((ext_vector_type(4)));
typedef unsigned short ushort4v __attribute__((ext_vector_type(4)));
typedef unsigned int uint4v __attribute__((ext_vector_type(4)));

#define NSTEP 1024

__device__ __forceinline__ unsigned short f2h(float f) {
    _Float16 h = (_Float16)f;
    return *(unsigned short*)&h;
}
__device__ __forceinline__ float tanh_fast(float x) {
    // 1 - 2/(e^{2x}+1): monotone, saturates to +-1 without NaN at extremes
    float e = __expf(2.f * x);
    return 1.f - 2.f / (e + 1.f);
}

// ---------------------------------------------------------------- GEMM1: xin = x @ Wi^T + bi
__global__ __launch_bounds__(256) void gemm_xin(
    const float* __restrict__ X, const float* __restrict__ Wi,
    const float* __restrict__ bi, float* __restrict__ xin)
{
    __shared__ unsigned short As[128][40];
    __shared__ unsigned short Bs[128][40];
    const int bm = blockIdx.x, bn = blockIdx.y;
    const int tid = threadIdx.x, w = tid >> 6, l = tid & 63;
    const int wm = w >> 1, wn = w & 1;
    f32x4 acc[4][4] = {};

    for (int kt = 0; kt < 512; kt += 32) {
        __syncthreads();
        #pragma unroll
        for (int j = 0; j < 4; j++) {
            int q = tid + 256 * j;
            int row = q >> 3, c4 = (q & 7) * 4;
            floatv4 va = *(const floatv4*)&X[(size_t)(bm * 128 + row) * 512 + kt + c4];
            floatv4 vb = *(const floatv4*)&Wi[(size_t)(bn * 128 + row) * 512 + kt + c4];
            ushort4v pa, pb;
            #pragma unroll
            for (int e = 0; e < 4; e++) { pa[e] = f2h(va[e]); pb[e] = f2h(vb[e]); }
            *(ushort4v*)&As[row][c4] = pa;
            *(ushort4v*)&Bs[row][c4] = pb;
        }
        __syncthreads();
        f16x8 a[4], b[4];
        #pragma unroll
        for (int i = 0; i < 4; i++)
            a[i] = *(const f16x8*)&As[wm * 64 + i * 16 + (l & 15)][(l >> 4) * 8];
        #pragma unroll
        for (int i = 0; i < 4; i++)
            b[i] = *(const f16x8*)&Bs[wn * 64 + i * 16 + (l & 15)][(l >> 4) * 8];
        #pragma unroll
        for (int i = 0; i < 4; i++)
            #pragma unroll
            for (int j = 0; j < 4; j++)
                acc[i][j] = __builtin_amdgcn_mfma_f32_16x16x32_f16(a[i], b[j], acc[i][j], 0, 0, 0);
    }
    #pragma unroll
    for (int i = 0; i < 4; i++)
        #pragma unroll
        for (int j = 0; j < 4; j++)
            #pragma unroll
            for (int r = 0; r < 4; r++) {
                int m = bm * 128 + wm * 64 + i * 16 + (l >> 4) * 4 + r;
                int n = bn * 128 + wn * 64 + j * 16 + (l & 15);
                int bb = m >> 10, tt = m & 1023;
                xin[((size_t)tt * 64 + bb) * 512 + n] = acc[i][j][r] + bi[n];
            }
}

// ---------------------------------------------------------------- GEMM3: outs = hs @ Wo^T + bo
__global__ __launch_bounds__(256) void gemm_out(
    const unsigned short* __restrict__ hs, const float* __restrict__ Wo,
    const float* __restrict__ bo, float* __restrict__ out)
{
    __shared__ unsigned short As[128][40];
    __shared__ unsigned short Bs[128][40];
    const int bm = blockIdx.x, bn = blockIdx.y;
    const int tid = threadIdx.x, w = tid >> 6, l = tid & 63;
    const int wm = w >> 1, wn = w & 1;
    f32x4 acc[4][4] = {};

    for (int kt = 0; kt < 512; kt += 32) {
        __syncthreads();
        #pragma unroll
        for (int j = 0; j < 2; j++) {
            int q = tid + 256 * j;
            int row = q >> 2, c8 = (q & 3) * 8;
            int r = bm * 128 + row;
            int ra = (r & 1023) * 64 + (r >> 10);
            f16x8 v = *(const f16x8*)&hs[(size_t)ra * 512 + kt + c8];
            *(f16x8*)&As[row][c8] = v;
        }
        #pragma unroll
        for (int j = 0; j < 4; j++) {
            int q = tid + 256 * j;
            int row = q >> 3, c4 = (q & 7) * 4;
            floatv4 vb = *(const floatv4*)&Wo[(size_t)(bn * 128 + row) * 512 + kt + c4];
            ushort4v pb;
            #pragma unroll
            for (int e = 0; e < 4; e++) pb[e] = f2h(vb[e]);
            *(ushort4v*)&Bs[row][c4] = pb;
        }
        __syncthreads();
        f16x8 a[4], b[4];
        #pragma unroll
        for (int i = 0; i < 4; i++)
            a[i] = *(const f16x8*)&As[wm * 64 + i * 16 + (l & 15)][(l >> 4) * 8];
        #pragma unroll
        for (int i = 0; i < 4; i++)
            b[i] = *(const f16x8*)&Bs[wn * 64 + i * 16 + (l & 15)][(l >> 4) * 8];
        #pragma unroll
        for (int i = 0; i < 4; i++)
            #pragma unroll
            for (int j = 0; j < 4; j++)
                acc[i][j] = __builtin_amdgcn_mfma_f32_16x16x32_f16(a[i], b[j], acc[i][j], 0, 0, 0);
    }
    #pragma unroll
    for (int i = 0; i < 4; i++)
        #pragma unroll
        for (int j = 0; j < 4; j++)
            #pragma unroll
            for (int r = 0; r < 4; r++) {
                int m = bm * 128 + wm * 64 + i * 16 + (l >> 4) * 4 + r;
                int n = bn * 128 + wn * 64 + j * 16 + (l & 15);
                out[(size_t)m * 512 + n] = acc[i][j][r] + bo[n];
            }
}

// ---------------------------------------------------------------- scan (exchange-free)
// 4 blocks; block g owns batches [g*16,+16), computes ALL 512 h-cols per step.
// Wave w owns n-cols [w*64,+64) (4 tiles of 16). Weights per wave: 64KB fp16,
// split VGPR (tiles 0,1: kt<11; tiles 2,3: kt<12 -> 46 frags = 184 regs) and
// LDS (18 chunks x 1KB). h: [16 rows][512] fp16 in LDS, XOR-swizzled
// (byte ^= (row&7)<<4) -> A-frag ds_read_b128 near the bank floor.
// waves_per_eu(2,2): pins the allocator budget at 256 VGPRs (LDS already caps
// the CU at 2 waves/EU; targeting 4 was pure spill).
__global__ __attribute__((amdgpu_flat_work_group_size(512, 512), amdgpu_waves_per_eu(2, 2)))
void scan_g(
    const float* __restrict__ Wr, const float* __restrict__ brv,
    const float* __restrict__ tau, const float* __restrict__ xin,
    unsigned short* __restrict__ hs, float* __restrict__ hfinal)
{
    const int g = blockIdx.x;
    const int tid = threadIdx.x, w = tid >> 6, l = tid & 63;

    __shared__ unsigned short wlds[73728];   // 144KB: 8 waves x 18 chunks x 512 ushort
    __shared__ unsigned short h16[8192];     // 16KB: h fp16 [16][512], XOR-swizzled

    // zero h16 (h0 = 0)
    ((uint4v*)h16)[tid] = uint4v{0, 0, 0, 0};
    ((uint4v*)h16)[tid + 512] = uint4v{0, 0, 0, 0};

    // ---- load weights: wave w, cols w*64 + tile*16 + (l&15), k = kt*32 + (l>>4)*8
    f16x8 wv0[11], wv1[11], wv2[12], wv3[12];
    #pragma unroll
    for (int kt = 0; kt < 16; kt++) {
        f16x8 f[4];
        #pragma unroll
        for (int tile = 0; tile < 4; tile++) {
            const float* p = &Wr[(size_t)(w * 64 + tile * 16 + (l & 15)) * 512 + kt * 32 + (l >> 4) * 8];
            #pragma unroll
            for (int e = 0; e < 8; e++) f[tile][e] = (_Float16)p[e];
        }
        if (kt < 11) { wv0[kt] = f[0]; wv1[kt] = f[1]; wv2[kt] = f[2]; wv3[kt] = f[3]; }
        else if (kt == 11) {
            wv2[11] = f[2]; wv3[11] = f[3];
            *(f16x8*)&wlds[(w * 18 + 0 + (kt - 11)) * 512 + l * 8] = f[0];
            *(f16x8*)&wlds[(w * 18 + 5 + (kt - 11)) * 512 + l * 8] = f[1];
        } else {
            *(f16x8*)&wlds[(w * 18 + 0  + (kt - 11)) * 512 + l * 8] = f[0];
            *(f16x8*)&wlds[(w * 18 + 5  + (kt - 11)) * 512 + l * 8] = f[1];
            *(f16x8*)&wlds[(w * 18 + 10 + (kt - 12)) * 512 + l * 8] = f[2];
            *(f16x8*)&wlds[(w * 18 + 14 + (kt - 12)) * 512 + l * 8] = f[3];
        }
    }

    // ---- per-col constants (4 tiles)
    float dd[4], dc[4], bb[4];
    #pragma unroll
    for (int tile = 0; tile < 4; tile++) {
        int col = w * 64 + tile * 16 + (l & 15);
        float s = 1.f / (1.f + __expf(-tau[col]));
        dd[tile] = s; dc[tile] = 1.f - s; bb[tile] = brv[col];
    }
    const int mr4 = (l >> 4) * 4;            // this thread's 4 batch rows
    // h state packed fp16 pairs: hpk[tile][rpair] = rows (2rp, 2rp+1)
    unsigned hpk[4][2] = {};

    __syncthreads();                          // h16 zeros + wlds ready

    for (int t = 0; t < NSTEP; ++t) {
        // xin for this step (independent loads; L3-resident; cover under MFMA)
        float xv[4][4];
        #pragma unroll
        for (int tile = 0; tile < 4; tile++)
            #pragma unroll
            for (int r = 0; r < 4; r++)
                xv[tile][r] = xin[((size_t)t * 64 + g * 16 + mr4 + r) * 512
                                  + w * 64 + tile * 16 + (l & 15)];

        // I = h @ Wr^T over all 512 k, 4 acc chains
        f32x4 acc[4] = {};
        #pragma unroll
        for (int kt = 0; kt < 11; kt++) {
            int abyte = (((l & 15) * 1024) + kt * 64 + ((l >> 4) * 16)) ^ ((l & 7) << 4);
            f16x8 ah = *(const f16x8*)((const char*)h16 + abyte);
            acc[0] = __builtin_amdgcn_mfma_f32_16x16x32_f16(ah, wv0[kt], acc[0], 0, 0, 0);
            acc[1] = __builtin_amdgcn_mfma_f32_16x16x32_f16(ah, wv1[kt], acc[1], 0, 0, 0);
            acc[2] = __builtin_amdgcn_mfma_f32_16x16x32_f16(ah, wv2[kt], acc[2], 0, 0, 0);
            acc[3] = __builtin_amdgcn_mfma_f32_16x16x32_f16(ah, wv3[kt], acc[3], 0, 0, 0);
        }
        {   // kt = 11: tiles 0,1 from LDS; tiles 2,3 from VGPR
            int abyte = (((l & 15) * 1024) + 11 * 64 + ((l >> 4) * 16)) ^ ((l & 7) << 4);
            f16x8 ah = *(const f16x8*)((const char*)h16 + abyte);
            f16x8 b0 = *(const f16x8*)&wlds[(w * 18 + 0) * 512 + l * 8];
            f16x8 b1 = *(const f16x8*)&wlds[(w * 18 + 5) * 512 + l * 8];
            acc[0] = __builtin_amdgcn_mfma_f32_16x16x32_f16(ah, b0, acc[0], 0, 0, 0);
            acc[1] = __builtin_amdgcn_mfma_f32_16x16x32_f16(ah, b1, acc[1], 0, 0, 0);
            acc[2] = __builtin_amdgcn_mfma_f32_16x16x32_f16(ah, wv2[11], acc[2], 0, 0, 0);
            acc[3] = __builtin_amdgcn_mfma_f32_16x16x32_f16(ah, wv3[11], acc[3], 0, 0, 0);
        }
        #pragma unroll
        for (int kt = 12; kt < 16; kt++) {
            int abyte = (((l & 15) * 1024) + kt * 64 + ((l >> 4) * 16)) ^ ((l & 7) << 4);
            f16x8 ah = *(const f16x8*)((const char*)h16 + abyte);
            f16x8 b0 = *(const f16x8*)&wlds[(w * 18 + 0  + (kt - 11)) * 512 + l * 8];
            f16x8 b1 = *(const f16x8*)&wlds[(w * 18 + 5  + (kt - 11)) * 512 + l * 8];
            f16x8 b2 = *(const f16x8*)&wlds[(w * 18 + 10 + (kt - 12)) * 512 + l * 8];
            f16x8 b3 = *(const f16x8*)&wlds[(w * 18 + 14 + (kt - 12)) * 512 + l * 8];
            acc[0] = __builtin_amdgcn_mfma_f32_16x16x32_f16(ah, b0, acc[0], 0, 0, 0);
            acc[1] = __builtin_amdgcn_mfma_f32_16x16x32_f16(ah, b1, acc[1], 0, 0, 0);
            acc[2] = __builtin_amdgcn_mfma_f32_16x16x32_f16(ah, b2, acc[2], 0, 0, 0);
            acc[3] = __builtin_amdgcn_mfma_f32_16x16x32_f16(ah, b3, acc[3], 0, 0, 0);
        }
        __syncthreads();                      // all reads of h_t complete

        // update h for this thread's 16 elems (4 tiles x 4 rows)
        #pragma unroll
        for (int tile = 0; tile < 4; tile++) {
            unsigned np[2];
            #pragma unroll
            for (int rp = 0; rp < 2; rp++) {
                unsigned pk = hpk[tile][rp];
                unsigned nv = 0;
                #pragma unroll
                for (int hbit = 0; hbit < 2; hbit++) {
                    int r = rp * 2 + hbit;
                    _Float16 holdh;
                    *(unsigned short*)&holdh = (unsigned short)((pk >> (hbit * 16)) & 0xffff);
                    float I = acc[tile][r] + xv[tile][r] + bb[tile];
                    float hn = dc[tile] * (float)holdh + dd[tile] * tanh_fast(I);
                    unsigned short hq = f2h(hn);
                    nv |= ((unsigned)hq) << (hbit * 16);
                    int row = mr4 + r, col = w * 64 + tile * 16 + (l & 15);
                    int byte = (row * 1024 + col * 2) ^ ((row & 7) << 4);
                    *(unsigned short*)((char*)h16 + byte) = hq;
                    hs[((size_t)t * 64 + g * 16 + row) * 512 + col] = hq;
                }
                np[rp] = nv;
            }
            hpk[tile][0] = np[0]; hpk[tile][1] = np[1];
        }
        __syncthreads();                      // h_{t+1} visible to all waves
    }

    // h_final fp32 (from packed fp16 state)
    #pragma unroll
    for (int tile = 0; tile < 4; tile++)
        #pragma unroll
        for (int r = 0; r < 4; r++) {
            _Float16 hv;
            *(unsigned short*)&hv = (unsigned short)((hpk[tile][r >> 1] >> ((r & 1) * 16)) & 0xffff);
            int col = w * 64 + tile * 16 + (l & 15);
            hfinal[(size_t)(g * 16 + mr4 + r) * 512 + col] = (float)hv;
        }
}

// ---------------------------------------------------------------- launch
extern "C" void kernel_launch(void* const* d_in, const int* in_sizes, int n_in,
                              void* d_out, int out_size, void* d_ws, size_t ws_size,
                              hipStream_t stream) {
    const float* x   = (const float*)d_in[0];
    const float* Wi  = (const float*)d_in[1];
    const float* bi  = (const float*)d_in[2];
    const float* Wr  = (const float*)d_in[3];
    const float* br  = (const float*)d_in[4];
    const float* tau = (const float*)d_in[5];
    const float* Wo  = (const float*)d_in[6];
    const float* bo  = (const float*)d_in[7];

    float* out    = (float*)d_out;
    float* xin    = (float*)d_out;                       // reuse outs region for xin [S,B,H] fp32
    float* hfinal = (float*)d_out + (size_t)33554432;    // after B*S*DOUT

    // ws: hs fp16 [S,B,H] (64 MiB). Nothing else.
    unsigned short* hs = (unsigned short*)d_ws;

    hipLaunchKernelGGL(gemm_xin, dim3(512, 4), dim3(256), 0, stream, x, Wi, bi, xin);
    hipLaunchKernelGGL(scan_g, dim3(4), dim3(512), 0, stream, Wr, br, tau, xin, hs, hfinal);
    hipLaunchKernelGGL(gemm_out, dim3(512, 4), dim3(256), 0, stream, hs, Wo, bo, out);
}